// Round 10
// baseline (241.332 us; speedup 1.0000x reference)
//
#include <hip/hip_runtime.h>

// Fused grouped 4-layer MLP: 64 models × 32768 tokens, d=64, fp32 in/out,
// f16 MFMA (fp32 accumulate) inside.
//
// R10 = R6's shared-W 32-token tile x R9's 8-wave blocks, register-disciplined.
// Evidence: R8 counters (VGPR=128, conflicts 0, no over-fetch, occupancy
// ~2 blocks/CU) + R9 flat at 16 waves/CU -> binding resource is per-CU: the
// LDS pipe. R7 structure issues 48 ds_read_b128 per 16-token tile (~123 us
// of LDS pipe per CU per pass at ~12 cyc/b128). This kernel halves that:
// two 16-token halves (A,B) inside one layer loop SHARE every W/bias ds_read
// (24 b128 per 32 tokens). Live set ~105 VGPR < 128 tier. R6 tested this
// structure but at 4-wave blocks near the tier edge (likely confounded).
//
// W fragments (32 KB) + bias (1 KB, exact f32) in LDS, shared by the block's
// 8 waves (same model). Model-interleaved token order: model's 64 waves sweep
// one contiguous 512-KB window per step, 16 steps. Orientation: D[f][tok];
// k-map k = 32*kk + 16*(j>>2) + 4*g + (j&3) for both operands; C/D layout:
// col=lane&15=token, row=4*(lane>>4)+reg=feature -> next layer's B fragment
// is a pure in-lane relu+cast repack. No inter-wave comms after staging.

typedef __attribute__((ext_vector_type(8))) _Float16 f16x8;
typedef __attribute__((ext_vector_type(2))) __fp16 fp16x2; // cvt_pkrtz's native type
typedef __attribute__((ext_vector_type(4))) float f32x4;

#define MODELS 64
#define LAYERS 4
#define DIM 64
#define TOKS_PER_MODEL 32768
#define THREADS 512
#define WAVES_PER_BLOCK 8
#define BLOCKS_PER_MODEL 8
#define WAVES_PER_MODEL (BLOCKS_PER_MODEL * WAVES_PER_BLOCK)     // 64
#define TILE_TOKS 32
#define STEPS (TOKS_PER_MODEL / (WAVES_PER_MODEL * TILE_TOKS))   // 16
#define STEP_FLOATS ((size_t)WAVES_PER_MODEL * TILE_TOKS * DIM)  // 131072 (512 KB)

#define WF_BYTES (LAYERS * 4 * 2 * 64 * 16)       // 32768: [l][t][kk][lane] f16x8
#define BIAS_OFF WF_BYTES                          // [l][64] f32
#define LDS_BYTES (WF_BYTES + LAYERS * DIM * 4)    // 33792

union H8 { f16x8 v; fp16x2 h2[4]; };

// 4 coalesced 16B loads for a 16-token half starting at float* P.
#define LOAD4(D0, D1, D2, D3, P)                                   \
    {                                                              \
        D0 = *(const f32x4*)((P) + 0);                             \
        D1 = *(const f32x4*)((P) + 16);                            \
        D2 = *(const f32x4*)((P) + 32);                            \
        D3 = *(const f32x4*)((P) + 48);                            \
    }

// cvt one 16-token half to f16 B-fragments Z0/Z1 (packed RTZ).
#define CVT_Z(Z0, Z1, X0, X1, X2, X3)                              \
    {                                                              \
        H8 z0u_, z1u_;                                             \
        z0u_.h2[0] = __builtin_amdgcn_cvt_pkrtz(X0[0], X0[1]);     \
        z0u_.h2[1] = __builtin_amdgcn_cvt_pkrtz(X0[2], X0[3]);     \
        z0u_.h2[2] = __builtin_amdgcn_cvt_pkrtz(X1[0], X1[1]);     \
        z0u_.h2[3] = __builtin_amdgcn_cvt_pkrtz(X1[2], X1[3]);     \
        z1u_.h2[0] = __builtin_amdgcn_cvt_pkrtz(X2[0], X2[1]);     \
        z1u_.h2[1] = __builtin_amdgcn_cvt_pkrtz(X2[2], X2[3]);     \
        z1u_.h2[2] = __builtin_amdgcn_cvt_pkrtz(X3[0], X3[1]);     \
        z1u_.h2[3] = __builtin_amdgcn_cvt_pkrtz(X3[2], X3[3]);     \
        Z0 = z0u_.v; Z1 = z1u_.v;                                  \
    }

// relu+cvt repack of acc -> next layer's B fragments for one half.
#define REPACK(Z0, Z1, ACC)                                                  \
    {                                                                        \
        H8 n0_, n1_;                                                         \
        _Pragma("unroll")                                                    \
        for (int t_ = 0; t_ < 2; ++t_) {                                     \
            n0_.h2[t_ * 2 + 0] = __builtin_amdgcn_cvt_pkrtz(                 \
                fmaxf(ACC[t_][0], 0.0f), fmaxf(ACC[t_][1], 0.0f));           \
            n0_.h2[t_ * 2 + 1] = __builtin_amdgcn_cvt_pkrtz(                 \
                fmaxf(ACC[t_][2], 0.0f), fmaxf(ACC[t_][3], 0.0f));           \
            n1_.h2[t_ * 2 + 0] = __builtin_amdgcn_cvt_pkrtz(                 \
                fmaxf(ACC[2 + t_][0], 0.0f), fmaxf(ACC[2 + t_][1], 0.0f));   \
            n1_.h2[t_ * 2 + 1] = __builtin_amdgcn_cvt_pkrtz(                 \
                fmaxf(ACC[2 + t_][2], 0.0f), fmaxf(ACC[2 + t_][3], 0.0f));   \
        }                                                                    \
        Z0 = n0_.v; Z1 = n1_.v;                                              \
    }

__global__ __launch_bounds__(THREADS, 2) void mlp4_fused(
    const float* __restrict__ x, const float* __restrict__ W,
    const float* __restrict__ b, float* __restrict__ out) {

    __shared__ __align__(16) unsigned char smem[LDS_BYTES];

    const int lane = threadIdx.x & 63;
    const int wave = threadIdx.x >> 6;          // 0..7
    const int c = lane & 15;   // token column (B/D) and W feature row (A)
    const int g = lane >> 4;   // k-group

    const int m   = blockIdx.x / BLOCKS_PER_MODEL;
    const int blk = blockIdx.x % BLOCKS_PER_MODEL;
    const int q   = blk * WAVES_PER_BLOCK + wave;   // wave slot in model, 0..63

    // ---- staging: wave w stages layer (w>>1), t-pair (w&1)*2..+1 ----
    // wf[l][t][kk] element j = f16(W[m][l][16t + c][32kk + 16*(j>>2) + 4g + (j&3)])
    {
        const int l = wave >> 1;
        const int tbase = (wave & 1) * 2;
        const float* Wl = W + ((size_t)m * LAYERS + l) * DIM * DIM;
        #pragma unroll
        for (int ti = 0; ti < 2; ++ti) {
            const int t = tbase + ti;
            const float* row = Wl + (size_t)(t * 16 + c) * DIM + 4 * g;
            f32x4 c0 = *(const f32x4*)(row + 0);
            f32x4 c1 = *(const f32x4*)(row + 16);
            f32x4 c2 = *(const f32x4*)(row + 32);
            f32x4 c3 = *(const f32x4*)(row + 48);
            H8 a0, a1;
            #pragma unroll
            for (int e = 0; e < 4; ++e) {
                a0.v[e]     = (_Float16)c0[e];  // RNE for weights (one-time)
                a0.v[4 + e] = (_Float16)c1[e];
                a1.v[e]     = (_Float16)c2[e];
                a1.v[4 + e] = (_Float16)c3[e];
            }
            *(f16x8*)(smem + ((size_t)((l * 4 + t) * 2 + 0) * 1024) + lane * 16) = a0.v;
            *(f16x8*)(smem + ((size_t)((l * 4 + t) * 2 + 1) * 1024) + lane * 16) = a1.v;
        }
        // bias layer l (staged by even waves), exact f32: 64 floats
        if ((wave & 1) == 0 && lane < 16) {
            const float* bl = b + ((size_t)m * LAYERS + l) * DIM + lane * 4;
            *(f32x4*)(smem + BIAS_OFF + l * 256 + lane * 16) = *(const f32x4*)bl;
        }
    }
    __syncthreads();

    // Lane's base: model m, wave-slot q's 32 tokens; half A = token q*32 + c,
    // half B = +16 tokens. Step stride = 2048 tokens (512 KB window/model).
    const float* xp = x   + ((size_t)m * TOKS_PER_MODEL + (size_t)q * TILE_TOKS) * DIM
                          + (size_t)(c * DIM + 4 * g);
    float*       op = out + ((size_t)m * TOKS_PER_MODEL + (size_t)q * TILE_TOKS) * DIM
                          + (size_t)(c * DIM + 4 * g);

    // X regs: current tile's raw f32 (two halves); refilled after cvt.
    f32x4 XA0, XA1, XA2, XA3, XB0, XB1, XB2, XB3;
    LOAD4(XA0, XA1, XA2, XA3, xp + 0 * (16 * DIM));
    LOAD4(XB0, XB1, XB2, XB3, xp + 1 * (16 * DIM));

    #pragma unroll 1
    for (int s = 0; s < STEPS; ++s) {
        // cvt current tile (both halves) to f16 fragments, freeing X regs
        f16x8 zA0, zA1, zB0, zB1;
        CVT_Z(zA0, zA1, XA0, XA1, XA2, XA3);
        CVT_Z(zB0, zB1, XB0, XB1, XB2, XB3);

        // issue next step's 8 loads into the SAME X regs (WAR: after cvt)
        const int nxt = (s + 1) & (STEPS - 1);
        const float* nx = xp + (size_t)nxt * STEP_FLOATS;
        LOAD4(XA0, XA1, XA2, XA3, nx + 0 * (16 * DIM));
        LOAD4(XB0, XB1, XB2, XB3, nx + 1 * (16 * DIM));

        // 4-layer chain, halves A and B sharing every W/bias ds_read
        f32x4 accA[4], accB[4];
        #pragma unroll
        for (int l = 0; l < LAYERS; ++l) {
            #pragma unroll
            for (int t = 0; t < 4; ++t) {
                f32x4 bv = *(const f32x4*)(smem + BIAS_OFF + l * 256 + t * 64 + g * 16);
                accA[t] = bv;
                accB[t] = bv;
            }
            #pragma unroll
            for (int t = 0; t < 4; ++t) {
                f16x8 w0 = *(const f16x8*)(smem + ((size_t)((l * 4 + t) * 2 + 0) * 1024) + lane * 16);
                accA[t] = __builtin_amdgcn_mfma_f32_16x16x32_f16(w0, zA0, accA[t], 0, 0, 0);
                accB[t] = __builtin_amdgcn_mfma_f32_16x16x32_f16(w0, zB0, accB[t], 0, 0, 0);
            }
            #pragma unroll
            for (int t = 0; t < 4; ++t) {
                f16x8 w1 = *(const f16x8*)(smem + ((size_t)((l * 4 + t) * 2 + 1) * 1024) + lane * 16);
                accA[t] = __builtin_amdgcn_mfma_f32_16x16x32_f16(w1, zA1, accA[t], 0, 0, 0);
                accB[t] = __builtin_amdgcn_mfma_f32_16x16x32_f16(w1, zB1, accB[t], 0, 0, 0);
            }
            if (l < LAYERS - 1) {
                REPACK(zA0, zA1, accA);
                REPACK(zB0, zB1, accB);
            }
        }

        // stores: f = 16t + 4g + r -> r contiguous -> dwordx4
        float* oA = op + (size_t)s * STEP_FLOATS;
        float* oB = oA + 16 * DIM;
        #pragma unroll
        for (int t = 0; t < 4; ++t) {
            f32x4 rA, rB;
            #pragma unroll
            for (int r = 0; r < 4; ++r) {
                rA[r] = fmaxf(accA[t][r], 0.0f);
                rB[r] = fmaxf(accB[t][r], 0.0f);
            }
            *(f32x4*)(oA + t * 16) = rA;
            *(f32x4*)(oB + t * 16) = rB;
        }
    }
}

extern "C" void kernel_launch(void* const* d_in, const int* in_sizes, int n_in,
                              void* d_out, int out_size, void* d_ws, size_t ws_size,
                              hipStream_t stream) {
    (void)in_sizes; (void)n_in; (void)out_size; (void)d_ws; (void)ws_size;
    const float* x = (const float*)d_in[0];
    const float* W = (const float*)d_in[1];
    const float* b = (const float*)d_in[2];
    float* out = (float*)d_out;
    mlp4_fused<<<dim3(MODELS * BLOCKS_PER_MODEL), dim3(THREADS), 0, stream>>>(x, W, b, out);
}

// Round 11
// 220.040 us; speedup vs baseline: 1.0968x; 1.0968x over previous
//
#include <hip/hip_runtime.h>

// Fused grouped 4-layer MLP: 64 models × 32768 tokens, d=64, fp32 in/out.
//
// R11: FULL-CONTIGUITY experiment. R4-R10 all plateau 228-242 us (~4.8 TB/s
// vs 6.3-6.6 proven); R8 showed pass-2 (LLC-fed) runs no faster than pass-1
// -> request-path bound, not DRAM. The untested variable: every global
// load/store is 16 scattered 64-B segments (fragment layout c*256+g*16).
// This round every global instruction is a contiguous 1 KB:
//   loads:  global_load_lds (linear LDS dest, pre-swizzled per-lane SOURCE)
//           -> ds_read_b128 at S = (c*256+t*64+g*16)^((c&7)<<4)  [conflict-free]
//   stores: ds_write_b128 at S -> ds_read_b128 at linOff^swz -> contiguous
//           global_store_dwordx4.
// Wave-private 2x4KB LDS bufs (P/Q): no barriers; vmcnt(4) counted waits
// (stores never drained). Bias in packed-bf16 regs (R1-proven accuracy).
// LDS 64 KB -> 2 blocks/CU; VGPR ~110 @ 256 cap -> no tier cliff.

typedef __attribute__((ext_vector_type(8))) _Float16 f16x8;
typedef __attribute__((ext_vector_type(2))) __fp16 fp16x2;
typedef __attribute__((ext_vector_type(4))) float f32x4;

#define MODELS 64
#define LAYERS 4
#define DIM 64
#define TOKS_PER_MODEL 32768
#define BLOCKS_PER_MODEL 16
#define WAVES_PER_BLOCK 4
#define WAVES_PER_MODEL 64
#define STEPS 32
#define STEP_FLOATS ((size_t)WAVES_PER_MODEL * 16 * DIM)   // 65536 floats
#define STEP_BYTES (STEP_FLOATS * 4)                        // 262144 B

#define WF_BYTES (LAYERS * 4 * 2 * 64 * 16)   // 32768
#define XBUF_OFF WF_BYTES                      // 4 waves × 2 bufs × 4096
#define LDS_BYTES (WF_BYTES + WAVES_PER_BLOCK * 2 * 4096)  // 65536

union H8 { f16x8 v; fp16x2 h2[4]; };

static __device__ __forceinline__ unsigned bf16bits(float f) {
    unsigned u = __builtin_bit_cast(unsigned, f);
    return (u + 0x7fffu + ((u >> 16) & 1u)) >> 16; // RNE
}

static __device__ __forceinline__ void dma16(const void* g, void* l) {
    __builtin_amdgcn_global_load_lds(
        (const __attribute__((address_space(1))) unsigned int*)g,
        (__attribute__((address_space(3))) unsigned int*)l, 16, 0, 0);
}

#define CVT_Z(Z0, Z1, X0, X1, X2, X3)                              \
    {                                                              \
        H8 z0u_, z1u_;                                             \
        z0u_.h2[0] = __builtin_amdgcn_cvt_pkrtz(X0[0], X0[1]);     \
        z0u_.h2[1] = __builtin_amdgcn_cvt_pkrtz(X0[2], X0[3]);     \
        z0u_.h2[2] = __builtin_amdgcn_cvt_pkrtz(X1[0], X1[1]);     \
        z0u_.h2[3] = __builtin_amdgcn_cvt_pkrtz(X1[2], X1[3]);     \
        z1u_.h2[0] = __builtin_amdgcn_cvt_pkrtz(X2[0], X2[1]);     \
        z1u_.h2[1] = __builtin_amdgcn_cvt_pkrtz(X2[2], X2[3]);     \
        z1u_.h2[2] = __builtin_amdgcn_cvt_pkrtz(X3[0], X3[1]);     \
        z1u_.h2[3] = __builtin_amdgcn_cvt_pkrtz(X3[2], X3[3]);     \
        Z0 = z0u_.v; Z1 = z1u_.v;                                  \
    }

__global__ __launch_bounds__(256, 2) void mlp4_fused(
    const float* __restrict__ x, const float* __restrict__ W,
    const float* __restrict__ b, float* __restrict__ out) {

    __shared__ __align__(16) unsigned char smem[LDS_BYTES];

    const int lane = threadIdx.x & 63;
    const int wave = threadIdx.x >> 6;
    const int c = lane & 15;   // token col (B/D) and W feature row (A)
    const int g = lane >> 4;   // k-group

    const int m   = blockIdx.x / BLOCKS_PER_MODEL;
    const int blk = blockIdx.x % BLOCKS_PER_MODEL;
    const int q   = blk * WAVES_PER_BLOCK + wave;   // wave slot in model

    // ---- stage this wave's layer (l = wave) of W into LDS (as R4) ----
    {
        const int l = wave;
        const float* Wl = W + ((size_t)m * LAYERS + l) * DIM * DIM;
        #pragma unroll
        for (int t = 0; t < 4; ++t) {
            const float* row = Wl + (size_t)(t * 16 + c) * DIM + 4 * g;
            f32x4 c0 = *(const f32x4*)(row + 0);
            f32x4 c1 = *(const f32x4*)(row + 16);
            f32x4 c2 = *(const f32x4*)(row + 32);
            f32x4 c3 = *(const f32x4*)(row + 48);
            H8 a0, a1;
            #pragma unroll
            for (int e = 0; e < 4; ++e) {
                a0.v[e]     = (_Float16)c0[e];
                a0.v[4 + e] = (_Float16)c1[e];
                a1.v[e]     = (_Float16)c2[e];
                a1.v[4 + e] = (_Float16)c3[e];
            }
            *(f16x8*)(smem + ((size_t)((l * 4 + t) * 2 + 0) * 1024) + lane * 16) = a0.v;
            *(f16x8*)(smem + ((size_t)((l * 4 + t) * 2 + 1) * 1024) + lane * 16) = a1.v;
        }
    }

    // ---- bias in registers, packed 2×bf16 (R1-proven; absmax unchanged) ----
    unsigned bpk[LAYERS][8];
    {
        const float* bm = b + (size_t)m * LAYERS * DIM;
        #pragma unroll
        for (int l = 0; l < LAYERS; ++l)
            #pragma unroll
            for (int t = 0; t < 4; ++t)
                #pragma unroll
                for (int p2 = 0; p2 < 2; ++p2) {
                    unsigned r0 = bf16bits(bm[l * DIM + t * 16 + 4 * g + 2 * p2]);
                    unsigned r1 = bf16bits(bm[l * DIM + t * 16 + 4 * g + 2 * p2 + 1]);
                    bpk[l][t * 2 + p2] = (r1 << 16) | r0;
                }
    }
    __syncthreads();

    // ---- per-lane offsets ----
    // fragment slots (read x / write out): S(c,t,g) = (c*256+t*64+g*16) ^ ((c&7)<<4)
    int frOff[4];
    #pragma unroll
    for (int t = 0; t < 4; ++t)
        frOff[t] = (c * 256 + t * 64 + g * 16) ^ ((c & 7) << 4);

    // DMA source / bounce-read: slot kk*1024 + lane*16 holds logical chunk:
    //   cc = kk*4 + (lane>>4); u = lane&15; v = (u&8)|((u&7)^(cc&7));
    //   logical byte L = cc*256 + (v>>2)*64 + (v&3)*16
    int srcOff[4], brOff[4];
    #pragma unroll
    for (int kk = 0; kk < 4; ++kk) {
        const int cc = kk * 4 + (lane >> 4);
        const int u  = lane & 15;
        const int v  = (u & 8) | ((u & 7) ^ (cc & 7));
        srcOff[kk] = cc * 256 + (v >> 2) * 64 + (v & 3) * 16;           // global <-> linear slot
        brOff[kk]  = (kk * 1024 + lane * 16) ^ ((cc & 7) << 4);          // swizzled slot holding linear chunk
    }

    const char* xTile = (const char*)(x + ((size_t)m * TOKS_PER_MODEL + (size_t)q * 16) * DIM);
    char*       oBase = (char*)(out + ((size_t)m * TOKS_PER_MODEL + (size_t)q * 16) * DIM) + lane * 16;
    unsigned char* xb = smem + XBUF_OFF + wave * 8192;   // two 4 KB bufs

    // prologue: DMA tile 0 into buf0, drain
    #pragma unroll
    for (int kk = 0; kk < 4; ++kk)
        dma16(xTile + srcOff[kk], xb + kk * 1024);
    asm volatile("s_waitcnt vmcnt(0)" ::: "memory");

    int p = 0;
    #pragma unroll 1
    for (int s = 0; s < STEPS; ++s) {
        unsigned char* bufc = xb + p * 4096;

        // x fragments from LDS (conflict-free swizzled b128)
        f32x4 X0 = *(const f32x4*)(bufc + frOff[0]);
        f32x4 X1 = *(const f32x4*)(bufc + frOff[1]);
        f32x4 X2 = *(const f32x4*)(bufc + frOff[2]);
        f32x4 X3 = *(const f32x4*)(bufc + frOff[3]);

        // issue next step's DMA into the other buffer (contiguous 1 KB each)
        {
            const size_t ns = (size_t)((s + 1) & (STEPS - 1)) * STEP_BYTES;
            unsigned char* nb = xb + (p ^ 1) * 4096;
            #pragma unroll
            for (int kk = 0; kk < 4; ++kk)
                dma16(xTile + ns + srcOff[kk], nb + kk * 1024);
        }

        f16x8 z0, z1;
        CVT_Z(z0, z1, X0, X1, X2, X3);

        f32x4 acc[4];
        #pragma unroll
        for (int l = 0; l < LAYERS; ++l) {
            #pragma unroll
            for (int t = 0; t < 4; ++t) {
                unsigned p0 = bpk[l][t * 2], p1 = bpk[l][t * 2 + 1];
                acc[t][0] = __builtin_bit_cast(float, p0 << 16);
                acc[t][1] = __builtin_bit_cast(float, p0 & 0xffff0000u);
                acc[t][2] = __builtin_bit_cast(float, p1 << 16);
                acc[t][3] = __builtin_bit_cast(float, p1 & 0xffff0000u);
            }
            #pragma unroll
            for (int t = 0; t < 4; ++t) {
                f16x8 w0 = *(const f16x8*)(smem + ((size_t)((l * 4 + t) * 2 + 0) * 1024) + lane * 16);
                acc[t] = __builtin_amdgcn_mfma_f32_16x16x32_f16(w0, z0, acc[t], 0, 0, 0);
            }
            #pragma unroll
            for (int t = 0; t < 4; ++t) {
                f16x8 w1 = *(const f16x8*)(smem + ((size_t)((l * 4 + t) * 2 + 1) * 1024) + lane * 16);
                acc[t] = __builtin_amdgcn_mfma_f32_16x16x32_f16(w1, z1, acc[t], 0, 0, 0);
            }
            if (l < LAYERS - 1) {
                H8 n0, n1;
                #pragma unroll
                for (int t = 0; t < 2; ++t) {
                    n0.h2[t * 2 + 0] = __builtin_amdgcn_cvt_pkrtz(
                        fmaxf(acc[t][0], 0.0f), fmaxf(acc[t][1], 0.0f));
                    n0.h2[t * 2 + 1] = __builtin_amdgcn_cvt_pkrtz(
                        fmaxf(acc[t][2], 0.0f), fmaxf(acc[t][3], 0.0f));
                    n1.h2[t * 2 + 0] = __builtin_amdgcn_cvt_pkrtz(
                        fmaxf(acc[2 + t][0], 0.0f), fmaxf(acc[2 + t][1], 0.0f));
                    n1.h2[t * 2 + 1] = __builtin_amdgcn_cvt_pkrtz(
                        fmaxf(acc[2 + t][2], 0.0f), fmaxf(acc[2 + t][3], 0.0f));
                }
                z0 = n0.v;
                z1 = n1.v;
            }
        }

        // out bounce through bufc (x reads of it already consumed)
        #pragma unroll
        for (int t = 0; t < 4; ++t) {
            f32x4 res;
            #pragma unroll
            for (int r = 0; r < 4; ++r) res[r] = fmaxf(acc[t][r], 0.0f);
            *(f32x4*)(bufc + frOff[t]) = res;            // ds_write_b128, swizzled
        }
        asm volatile("s_waitcnt lgkmcnt(0)" ::: "memory");
        __builtin_amdgcn_sched_barrier(0);

        {
            char* o = oBase + (size_t)s * STEP_BYTES;
            f32x4 O0 = *(const f32x4*)(bufc + brOff[0]);
            f32x4 O1 = *(const f32x4*)(bufc + brOff[1]);
            f32x4 O2 = *(const f32x4*)(bufc + brOff[2]);
            f32x4 O3 = *(const f32x4*)(bufc + brOff[3]);
            *(f32x4*)(o + 0)    = O0;                    // contiguous 1 KB stores
            *(f32x4*)(o + 1024) = O1;
            *(f32x4*)(o + 2048) = O2;
            *(f32x4*)(o + 3072) = O3;
        }

        // drain next-tile DMA (older) but NOT the stores (newer): <=4 left
        asm volatile("s_waitcnt vmcnt(4)" ::: "memory");
        p ^= 1;
    }
}

extern "C" void kernel_launch(void* const* d_in, const int* in_sizes, int n_in,
                              void* d_out, int out_size, void* d_ws, size_t ws_size,
                              hipStream_t stream) {
    (void)in_sizes; (void)n_in; (void)out_size; (void)d_ws; (void)ws_size;
    const float* x = (const float*)d_in[0];
    const float* W = (const float*)d_in[1];
    const float* b = (const float*)d_in[2];
    float* out = (float*)d_out;
    mlp4_fused<<<dim3(MODELS * BLOCKS_PER_MODEL), dim3(256), 0, stream>>>(x, W, b, out);
}

// Round 12
// 216.191 us; speedup vs baseline: 1.1163x; 1.0178x over previous
//
#include <hip/hip_runtime.h>

// Fused grouped 4-layer MLP: 64 models × 32768 tokens, d=64, fp32 in/out.
//
// R12 = R11 + TRI-BUFFER (depth-2 outstanding tile loads). R11 (full
// contiguity via LDS transit) gave the first gain (228->220) but per-wave
// load MLP is depth-1: after issuing 4KB for tile s+1 the wave stalls at
// vmcnt with nothing else in flight -> ~32KB/CU outstanding -> ~5 TB/s cap
// (Little). This round: 3 x 4KB bufs/wave; iter s reads buf s%3, DMAs tile
// s+2 into buf (s+2)%3, computes, bounce-stores, waits vmcnt(8) (tile s+1
// ready; current DMA + stores stay in flight). Outstanding loads 2x.
// LDS 32KB W + 48KB bufs = 80KB -> still 2 blocks/CU: occupancy unchanged,
// load-depth is the single variable. Zero extra VGPRs (buffers in LDS).
//
// Contiguity recap (R11): loads global_load_lds dwordx4 (1KB contiguous per
// instr, pre-swizzled per-lane SOURCE, linear LDS dest) -> ds_read_b128 at
// S=(c*256+t*64+g*16)^((c&7)<<4) conflict-free; stores bounce ds_write(S) ->
// ds_read(linear^swz) -> contiguous global_store_dwordx4. Wave-private bufs,
// no barriers. Bias packed-bf16 in regs. MFMA D[f][tok]; k-map
// k=32kk+16(j>>2)+4g+(j&3) both operands; C/D col=lane&15, row=4*(lane>>4)+reg.

typedef __attribute__((ext_vector_type(8))) _Float16 f16x8;
typedef __attribute__((ext_vector_type(2))) __fp16 fp16x2;
typedef __attribute__((ext_vector_type(4))) float f32x4;

#define MODELS 64
#define LAYERS 4
#define DIM 64
#define TOKS_PER_MODEL 32768
#define BLOCKS_PER_MODEL 16
#define WAVES_PER_BLOCK 4
#define WAVES_PER_MODEL 64
#define STEPS 32
#define STEP_FLOATS ((size_t)WAVES_PER_MODEL * 16 * DIM)   // 65536 floats
#define STEP_BYTES (STEP_FLOATS * 4)                        // 262144 B

#define WF_BYTES (LAYERS * 4 * 2 * 64 * 16)   // 32768
#define XBUF_OFF WF_BYTES                      // 4 waves × 3 bufs × 4096
#define LDS_BYTES (WF_BYTES + WAVES_PER_BLOCK * 3 * 4096)  // 81920 (2 blocks/CU)

union H8 { f16x8 v; fp16x2 h2[4]; };

static __device__ __forceinline__ unsigned bf16bits(float f) {
    unsigned u = __builtin_bit_cast(unsigned, f);
    return (u + 0x7fffu + ((u >> 16) & 1u)) >> 16; // RNE
}

static __device__ __forceinline__ void dma16(const void* g, void* l) {
    __builtin_amdgcn_global_load_lds(
        (const __attribute__((address_space(1))) unsigned int*)g,
        (__attribute__((address_space(3))) unsigned int*)l, 16, 0, 0);
}

#define CVT_Z(Z0, Z1, X0, X1, X2, X3)                              \
    {                                                              \
        H8 z0u_, z1u_;                                             \
        z0u_.h2[0] = __builtin_amdgcn_cvt_pkrtz(X0[0], X0[1]);     \
        z0u_.h2[1] = __builtin_amdgcn_cvt_pkrtz(X0[2], X0[3]);     \
        z0u_.h2[2] = __builtin_amdgcn_cvt_pkrtz(X1[0], X1[1]);     \
        z0u_.h2[3] = __builtin_amdgcn_cvt_pkrtz(X1[2], X1[3]);     \
        z1u_.h2[0] = __builtin_amdgcn_cvt_pkrtz(X2[0], X2[1]);     \
        z1u_.h2[1] = __builtin_amdgcn_cvt_pkrtz(X2[2], X2[3]);     \
        z1u_.h2[2] = __builtin_amdgcn_cvt_pkrtz(X3[0], X3[1]);     \
        z1u_.h2[3] = __builtin_amdgcn_cvt_pkrtz(X3[2], X3[3]);     \
        Z0 = z0u_.v; Z1 = z1u_.v;                                  \
    }

__global__ __launch_bounds__(256, 2) void mlp4_fused(
    const float* __restrict__ x, const float* __restrict__ W,
    const float* __restrict__ b, float* __restrict__ out) {

    __shared__ __align__(16) unsigned char smem[LDS_BYTES];

    const int lane = threadIdx.x & 63;
    const int wave = threadIdx.x >> 6;
    const int c = lane & 15;   // token col (B/D) and W feature row (A)
    const int g = lane >> 4;   // k-group

    const int m   = blockIdx.x / BLOCKS_PER_MODEL;
    const int blk = blockIdx.x % BLOCKS_PER_MODEL;
    const int q   = blk * WAVES_PER_BLOCK + wave;   // wave slot in model

    // ---- stage this wave's layer (l = wave) of W into LDS ----
    {
        const int l = wave;
        const float* Wl = W + ((size_t)m * LAYERS + l) * DIM * DIM;
        #pragma unroll
        for (int t = 0; t < 4; ++t) {
            const float* row = Wl + (size_t)(t * 16 + c) * DIM + 4 * g;
            f32x4 c0 = *(const f32x4*)(row + 0);
            f32x4 c1 = *(const f32x4*)(row + 16);
            f32x4 c2 = *(const f32x4*)(row + 32);
            f32x4 c3 = *(const f32x4*)(row + 48);
            H8 a0, a1;
            #pragma unroll
            for (int e = 0; e < 4; ++e) {
                a0.v[e]     = (_Float16)c0[e];
                a0.v[4 + e] = (_Float16)c1[e];
                a1.v[e]     = (_Float16)c2[e];
                a1.v[4 + e] = (_Float16)c3[e];
            }
            *(f16x8*)(smem + ((size_t)((l * 4 + t) * 2 + 0) * 1024) + lane * 16) = a0.v;
            *(f16x8*)(smem + ((size_t)((l * 4 + t) * 2 + 1) * 1024) + lane * 16) = a1.v;
        }
    }

    // ---- bias in registers, packed 2×bf16 ----
    unsigned bpk[LAYERS][8];
    {
        const float* bm = b + (size_t)m * LAYERS * DIM;
        #pragma unroll
        for (int l = 0; l < LAYERS; ++l)
            #pragma unroll
            for (int t = 0; t < 4; ++t)
                #pragma unroll
                for (int p2 = 0; p2 < 2; ++p2) {
                    unsigned r0 = bf16bits(bm[l * DIM + t * 16 + 4 * g + 2 * p2]);
                    unsigned r1 = bf16bits(bm[l * DIM + t * 16 + 4 * g + 2 * p2 + 1]);
                    bpk[l][t * 2 + p2] = (r1 << 16) | r0;
                }
    }
    __syncthreads();

    // ---- per-lane offsets (as R11, verified) ----
    int frOff[4];
    #pragma unroll
    for (int t = 0; t < 4; ++t)
        frOff[t] = (c * 256 + t * 64 + g * 16) ^ ((c & 7) << 4);

    int srcOff[4], brOff[4];
    #pragma unroll
    for (int kk = 0; kk < 4; ++kk) {
        const int cc = kk * 4 + (lane >> 4);
        const int u  = lane & 15;
        const int v  = (u & 8) | ((u & 7) ^ (cc & 7));
        srcOff[kk] = cc * 256 + (v >> 2) * 64 + (v & 3) * 16;
        brOff[kk]  = (kk * 1024 + lane * 16) ^ ((cc & 7) << 4);
    }

    const char* xTile = (const char*)(x + ((size_t)m * TOKS_PER_MODEL + (size_t)q * 16) * DIM);
    char*       oBase = (char*)(out + ((size_t)m * TOKS_PER_MODEL + (size_t)q * 16) * DIM) + lane * 16;
    unsigned char* xb = smem + XBUF_OFF + wave * (3 * 4096);  // three 4 KB bufs

    // prologue: DMA tile 0 -> b0, tile 1 -> b1; wait tile 0 (vmcnt(4) leaves tile-1 in flight)
    #pragma unroll
    for (int kk = 0; kk < 4; ++kk)
        dma16(xTile + srcOff[kk], xb + kk * 1024);
    #pragma unroll
    for (int kk = 0; kk < 4; ++kk)
        dma16(xTile + STEP_BYTES + srcOff[kk], xb + 4096 + kk * 1024);
    asm volatile("s_waitcnt vmcnt(4)" ::: "memory");

    int p = 0;
    #pragma unroll 1
    for (int s = 0; s < STEPS; ++s) {
        unsigned char* bufc = xb + p * 4096;

        // x fragments from LDS (conflict-free swizzled b128)
        f32x4 X0 = *(const f32x4*)(bufc + frOff[0]);
        f32x4 X1 = *(const f32x4*)(bufc + frOff[1]);
        f32x4 X2 = *(const f32x4*)(bufc + frOff[2]);
        f32x4 X3 = *(const f32x4*)(bufc + frOff[3]);

        // issue DMA for tile s+2 into buf (p+2)%3 (holds tile s-1: fully consumed)
        {
            int pd = p + 2; if (pd >= 3) pd -= 3;
            const int tn = (s + 2 < STEPS) ? (s + 2) : (STEPS - 1); // clamp: discard tail
            const size_t ns = (size_t)tn * STEP_BYTES;
            unsigned char* nb = xb + pd * 4096;
            #pragma unroll
            for (int kk = 0; kk < 4; ++kk)
                dma16(xTile + ns + srcOff[kk], nb + kk * 1024);
        }

        f16x8 z0, z1;
        CVT_Z(z0, z1, X0, X1, X2, X3);

        f32x4 acc[4];
        #pragma unroll
        for (int l = 0; l < LAYERS; ++l) {
            #pragma unroll
            for (int t = 0; t < 4; ++t) {
                unsigned p0 = bpk[l][t * 2], p1 = bpk[l][t * 2 + 1];
                acc[t][0] = __builtin_bit_cast(float, p0 << 16);
                acc[t][1] = __builtin_bit_cast(float, p0 & 0xffff0000u);
                acc[t][2] = __builtin_bit_cast(float, p1 << 16);
                acc[t][3] = __builtin_bit_cast(float, p1 & 0xffff0000u);
            }
            #pragma unroll
            for (int t = 0; t < 4; ++t) {
                f16x8 w0 = *(const f16x8*)(smem + ((size_t)((l * 4 + t) * 2 + 0) * 1024) + lane * 16);
                acc[t] = __builtin_amdgcn_mfma_f32_16x16x32_f16(w0, z0, acc[t], 0, 0, 0);
            }
            #pragma unroll
            for (int t = 0; t < 4; ++t) {
                f16x8 w1 = *(const f16x8*)(smem + ((size_t)((l * 4 + t) * 2 + 1) * 1024) + lane * 16);
                acc[t] = __builtin_amdgcn_mfma_f32_16x16x32_f16(w1, z1, acc[t], 0, 0, 0);
            }
            if (l < LAYERS - 1) {
                H8 n0, n1;
                #pragma unroll
                for (int t = 0; t < 2; ++t) {
                    n0.h2[t * 2 + 0] = __builtin_amdgcn_cvt_pkrtz(
                        fmaxf(acc[t][0], 0.0f), fmaxf(acc[t][1], 0.0f));
                    n0.h2[t * 2 + 1] = __builtin_amdgcn_cvt_pkrtz(
                        fmaxf(acc[t][2], 0.0f), fmaxf(acc[t][3], 0.0f));
                    n1.h2[t * 2 + 0] = __builtin_amdgcn_cvt_pkrtz(
                        fmaxf(acc[2 + t][0], 0.0f), fmaxf(acc[2 + t][1], 0.0f));
                    n1.h2[t * 2 + 1] = __builtin_amdgcn_cvt_pkrtz(
                        fmaxf(acc[2 + t][2], 0.0f), fmaxf(acc[2 + t][3], 0.0f));
                }
                z0 = n0.v;
                z1 = n1.v;
            }
        }

        // out bounce through bufc (x reads of it already consumed)
        #pragma unroll
        for (int t = 0; t < 4; ++t) {
            f32x4 res;
            #pragma unroll
            for (int r = 0; r < 4; ++r) res[r] = fmaxf(acc[t][r], 0.0f);
            *(f32x4*)(bufc + frOff[t]) = res;            // ds_write_b128, swizzled
        }
        asm volatile("s_waitcnt lgkmcnt(0)" ::: "memory");
        __builtin_amdgcn_sched_barrier(0);

        {
            char* o = oBase + (size_t)s * STEP_BYTES;
            f32x4 O0 = *(const f32x4*)(bufc + brOff[0]);
            f32x4 O1 = *(const f32x4*)(bufc + brOff[1]);
            f32x4 O2 = *(const f32x4*)(bufc + brOff[2]);
            f32x4 O3 = *(const f32x4*)(bufc + brOff[3]);
            *(f32x4*)(o + 0)    = O0;                    // contiguous 1 KB stores
            *(f32x4*)(o + 1024) = O1;
            *(f32x4*)(o + 2048) = O2;
            *(f32x4*)(o + 3072) = O3;
        }

        // wait tile s+1's DMA (and retire old stores); keep newest DMA + stores in flight
        asm volatile("s_waitcnt vmcnt(8)" ::: "memory");
        p = (p + 1 == 3) ? 0 : p + 1;
    }
}

extern "C" void kernel_launch(void* const* d_in, const int* in_sizes, int n_in,
                              void* d_out, int out_size, void* d_ws, size_t ws_size,
                              hipStream_t stream) {
    (void)in_sizes; (void)n_in; (void)out_size; (void)d_ws; (void)ws_size;
    const float* x = (const float*)d_in[0];
    const float* W = (const float*)d_in[1];
    const float* b = (const float*)d_in[2];
    float* out = (float*)d_out;
    mlp4_fused<<<dim3(MODELS * BLOCKS_PER_MODEL), dim3(256), 0, stream>>>(x, W, b, out);
}

// Round 13
// 208.061 us; speedup vs baseline: 1.1599x; 1.0391x over previous
//
#include <hip/hip_runtime.h>

// Fused grouped 4-layer MLP: 64 models × 32768 tokens, d=64, fp32 in/out.
//
// R13 = R12 + (a) CORRECT counted vmcnt + (b) non-temporal hints.
// (a) vmcnt retires in order and counts stores: R12's vmcnt(8) waited for the
//     PREVIOUS ITERATION'S STORES to ack at L2 every iteration. Steady-state
//     window at the wait: [s+1 DMA x4][prev stores x4][s+2 DMA x4][stores x4];
//     vmcnt(12) = "all but newest 12 done" = exactly tile s+1's DMA, stores
//     stay in flight. Iter 0 window is 8 -> vmcnt(8) there (branch).
// (b) x read once, out written once: DMA aux=2 (NT) + nontemporal stores ->
//     no L2 allocation for 1 GB of dead lines.
// Rest identical to R12: tri-buffer (depth-2 loads), full contiguity via LDS
// transit, wave-private bufs, no barriers, bias packed-bf16 in regs,
// W f16 fragments in LDS. LDS 80KB -> 2 blocks/CU. VGPR ~110.

typedef __attribute__((ext_vector_type(8))) _Float16 f16x8;
typedef __attribute__((ext_vector_type(2))) __fp16 fp16x2;
typedef __attribute__((ext_vector_type(4))) float f32x4;

#define MODELS 64
#define LAYERS 4
#define DIM 64
#define TOKS_PER_MODEL 32768
#define BLOCKS_PER_MODEL 16
#define WAVES_PER_BLOCK 4
#define WAVES_PER_MODEL 64
#define STEPS 32
#define STEP_FLOATS ((size_t)WAVES_PER_MODEL * 16 * DIM)   // 65536 floats
#define STEP_BYTES (STEP_FLOATS * 4)                        // 262144 B

#define WF_BYTES (LAYERS * 4 * 2 * 64 * 16)   // 32768
#define XBUF_OFF WF_BYTES                      // 4 waves × 3 bufs × 4096
#define LDS_BYTES (WF_BYTES + WAVES_PER_BLOCK * 3 * 4096)  // 81920 (2 blocks/CU)

union H8 { f16x8 v; fp16x2 h2[4]; };

static __device__ __forceinline__ unsigned bf16bits(float f) {
    unsigned u = __builtin_bit_cast(unsigned, f);
    return (u + 0x7fffu + ((u >> 16) & 1u)) >> 16; // RNE
}

// NT (aux=2: CPol NT bit on gfx9xx) streaming DMA: global -> LDS, 16B/lane.
static __device__ __forceinline__ void dma16(const void* g, void* l) {
    __builtin_amdgcn_global_load_lds(
        (const __attribute__((address_space(1))) unsigned int*)g,
        (__attribute__((address_space(3))) unsigned int*)l, 16, 0, 2);
}

#define CVT_Z(Z0, Z1, X0, X1, X2, X3)                              \
    {                                                              \
        H8 z0u_, z1u_;                                             \
        z0u_.h2[0] = __builtin_amdgcn_cvt_pkrtz(X0[0], X0[1]);     \
        z0u_.h2[1] = __builtin_amdgcn_cvt_pkrtz(X0[2], X0[3]);     \
        z0u_.h2[2] = __builtin_amdgcn_cvt_pkrtz(X1[0], X1[1]);     \
        z0u_.h2[3] = __builtin_amdgcn_cvt_pkrtz(X1[2], X1[3]);     \
        z1u_.h2[0] = __builtin_amdgcn_cvt_pkrtz(X2[0], X2[1]);     \
        z1u_.h2[1] = __builtin_amdgcn_cvt_pkrtz(X2[2], X2[3]);     \
        z1u_.h2[2] = __builtin_amdgcn_cvt_pkrtz(X3[0], X3[1]);     \
        z1u_.h2[3] = __builtin_amdgcn_cvt_pkrtz(X3[2], X3[3]);     \
        Z0 = z0u_.v; Z1 = z1u_.v;                                  \
    }

__global__ __launch_bounds__(256, 2) void mlp4_fused(
    const float* __restrict__ x, const float* __restrict__ W,
    const float* __restrict__ b, float* __restrict__ out) {

    __shared__ __align__(16) unsigned char smem[LDS_BYTES];

    const int lane = threadIdx.x & 63;
    const int wave = threadIdx.x >> 6;
    const int c = lane & 15;   // token col (B/D) and W feature row (A)
    const int g = lane >> 4;   // k-group

    const int m   = blockIdx.x / BLOCKS_PER_MODEL;
    const int blk = blockIdx.x % BLOCKS_PER_MODEL;
    const int q   = blk * WAVES_PER_BLOCK + wave;   // wave slot in model

    // ---- stage this wave's layer (l = wave) of W into LDS ----
    {
        const int l = wave;
        const float* Wl = W + ((size_t)m * LAYERS + l) * DIM * DIM;
        #pragma unroll
        for (int t = 0; t < 4; ++t) {
            const float* row = Wl + (size_t)(t * 16 + c) * DIM + 4 * g;
            f32x4 c0 = *(const f32x4*)(row + 0);
            f32x4 c1 = *(const f32x4*)(row + 16);
            f32x4 c2 = *(const f32x4*)(row + 32);
            f32x4 c3 = *(const f32x4*)(row + 48);
            H8 a0, a1;
            #pragma unroll
            for (int e = 0; e < 4; ++e) {
                a0.v[e]     = (_Float16)c0[e];
                a0.v[4 + e] = (_Float16)c1[e];
                a1.v[e]     = (_Float16)c2[e];
                a1.v[4 + e] = (_Float16)c3[e];
            }
            *(f16x8*)(smem + ((size_t)((l * 4 + t) * 2 + 0) * 1024) + lane * 16) = a0.v;
            *(f16x8*)(smem + ((size_t)((l * 4 + t) * 2 + 1) * 1024) + lane * 16) = a1.v;
        }
    }

    // ---- bias in registers, packed 2×bf16 ----
    unsigned bpk[LAYERS][8];
    {
        const float* bm = b + (size_t)m * LAYERS * DIM;
        #pragma unroll
        for (int l = 0; l < LAYERS; ++l)
            #pragma unroll
            for (int t = 0; t < 4; ++t)
                #pragma unroll
                for (int p2 = 0; p2 < 2; ++p2) {
                    unsigned r0 = bf16bits(bm[l * DIM + t * 16 + 4 * g + 2 * p2]);
                    unsigned r1 = bf16bits(bm[l * DIM + t * 16 + 4 * g + 2 * p2 + 1]);
                    bpk[l][t * 2 + p2] = (r1 << 16) | r0;
                }
    }
    __syncthreads();

    // ---- per-lane offsets (R11-verified) ----
    int frOff[4];
    #pragma unroll
    for (int t = 0; t < 4; ++t)
        frOff[t] = (c * 256 + t * 64 + g * 16) ^ ((c & 7) << 4);

    int srcOff[4], brOff[4];
    #pragma unroll
    for (int kk = 0; kk < 4; ++kk) {
        const int cc = kk * 4 + (lane >> 4);
        const int u  = lane & 15;
        const int v  = (u & 8) | ((u & 7) ^ (cc & 7));
        srcOff[kk] = cc * 256 + (v >> 2) * 64 + (v & 3) * 16;
        brOff[kk]  = (kk * 1024 + lane * 16) ^ ((cc & 7) << 4);
    }

    const char* xTile = (const char*)(x + ((size_t)m * TOKS_PER_MODEL + (size_t)q * 16) * DIM);
    char*       oBase = (char*)(out + ((size_t)m * TOKS_PER_MODEL + (size_t)q * 16) * DIM) + lane * 16;
    unsigned char* xb = smem + XBUF_OFF + wave * (3 * 4096);  // three 4 KB bufs

    // prologue: DMA tile 0 -> b0, tile 1 -> b1; wait tile 0 only
    #pragma unroll
    for (int kk = 0; kk < 4; ++kk)
        dma16(xTile + srcOff[kk], xb + kk * 1024);
    #pragma unroll
    for (int kk = 0; kk < 4; ++kk)
        dma16(xTile + STEP_BYTES + srcOff[kk], xb + 4096 + kk * 1024);
    asm volatile("s_waitcnt vmcnt(4)" ::: "memory");

    int p = 0;
    #pragma unroll 1
    for (int s = 0; s < STEPS; ++s) {
        unsigned char* bufc = xb + p * 4096;

        // x fragments from LDS (conflict-free swizzled b128)
        f32x4 X0 = *(const f32x4*)(bufc + frOff[0]);
        f32x4 X1 = *(const f32x4*)(bufc + frOff[1]);
        f32x4 X2 = *(const f32x4*)(bufc + frOff[2]);
        f32x4 X3 = *(const f32x4*)(bufc + frOff[3]);

        // issue DMA for tile s+2 into buf (p+2)%3 (holds tile s-1: consumed)
        {
            int pd = p + 2; if (pd >= 3) pd -= 3;
            const int tn = (s + 2 < STEPS) ? (s + 2) : (STEPS - 1); // clamp tail
            const size_t ns = (size_t)tn * STEP_BYTES;
            unsigned char* nb = xb + pd * 4096;
            #pragma unroll
            for (int kk = 0; kk < 4; ++kk)
                dma16(xTile + ns + srcOff[kk], nb + kk * 1024);
        }

        f16x8 z0, z1;
        CVT_Z(z0, z1, X0, X1, X2, X3);

        f32x4 acc[4];
        #pragma unroll
        for (int l = 0; l < LAYERS; ++l) {
            #pragma unroll
            for (int t = 0; t < 4; ++t) {
                unsigned p0 = bpk[l][t * 2], p1 = bpk[l][t * 2 + 1];
                acc[t][0] = __builtin_bit_cast(float, p0 << 16);
                acc[t][1] = __builtin_bit_cast(float, p0 & 0xffff0000u);
                acc[t][2] = __builtin_bit_cast(float, p1 << 16);
                acc[t][3] = __builtin_bit_cast(float, p1 & 0xffff0000u);
            }
            #pragma unroll
            for (int t = 0; t < 4; ++t) {
                f16x8 w0 = *(const f16x8*)(smem + ((size_t)((l * 4 + t) * 2 + 0) * 1024) + lane * 16);
                acc[t] = __builtin_amdgcn_mfma_f32_16x16x32_f16(w0, z0, acc[t], 0, 0, 0);
            }
            #pragma unroll
            for (int t = 0; t < 4; ++t) {
                f16x8 w1 = *(const f16x8*)(smem + ((size_t)((l * 4 + t) * 2 + 1) * 1024) + lane * 16);
                acc[t] = __builtin_amdgcn_mfma_f32_16x16x32_f16(w1, z1, acc[t], 0, 0, 0);
            }
            if (l < LAYERS - 1) {
                H8 n0, n1;
                #pragma unroll
                for (int t = 0; t < 2; ++t) {
                    n0.h2[t * 2 + 0] = __builtin_amdgcn_cvt_pkrtz(
                        fmaxf(acc[t][0], 0.0f), fmaxf(acc[t][1], 0.0f));
                    n0.h2[t * 2 + 1] = __builtin_amdgcn_cvt_pkrtz(
                        fmaxf(acc[t][2], 0.0f), fmaxf(acc[t][3], 0.0f));
                    n1.h2[t * 2 + 0] = __builtin_amdgcn_cvt_pkrtz(
                        fmaxf(acc[2 + t][0], 0.0f), fmaxf(acc[2 + t][1], 0.0f));
                    n1.h2[t * 2 + 1] = __builtin_amdgcn_cvt_pkrtz(
                        fmaxf(acc[2 + t][2], 0.0f), fmaxf(acc[2 + t][3], 0.0f));
                }
                z0 = n0.v;
                z1 = n1.v;
            }
        }

        // out bounce through bufc
        #pragma unroll
        for (int t = 0; t < 4; ++t) {
            f32x4 res;
            #pragma unroll
            for (int r = 0; r < 4; ++r) res[r] = fmaxf(acc[t][r], 0.0f);
            *(f32x4*)(bufc + frOff[t]) = res;            // ds_write_b128, swizzled
        }
        asm volatile("s_waitcnt lgkmcnt(0)" ::: "memory");
        __builtin_amdgcn_sched_barrier(0);

        {
            char* o = oBase + (size_t)s * STEP_BYTES;
            f32x4 O0 = *(const f32x4*)(bufc + brOff[0]);
            f32x4 O1 = *(const f32x4*)(bufc + brOff[1]);
            f32x4 O2 = *(const f32x4*)(bufc + brOff[2]);
            f32x4 O3 = *(const f32x4*)(bufc + brOff[3]);
            __builtin_nontemporal_store(O0, (f32x4*)(o + 0));     // contiguous 1 KB, NT
            __builtin_nontemporal_store(O1, (f32x4*)(o + 1024));
            __builtin_nontemporal_store(O2, (f32x4*)(o + 2048));
            __builtin_nontemporal_store(O3, (f32x4*)(o + 3072));
        }

        // counted wait: require ONLY tile s+1's DMA (all but newest 12 done);
        // prev-iter stores stay in flight. Iter 0's window is 8 (no prev stores).
        if (s == 0) asm volatile("s_waitcnt vmcnt(8)"  ::: "memory");
        else        asm volatile("s_waitcnt vmcnt(12)" ::: "memory");
        p = (p + 1 == 3) ? 0 : p + 1;
    }
}

extern "C" void kernel_launch(void* const* d_in, const int* in_sizes, int n_in,
                              void* d_out, int out_size, void* d_ws, size_t ws_size,
                              hipStream_t stream) {
    (void)in_sizes; (void)n_in; (void)out_size; (void)d_ws; (void)ws_size;
    const float* x = (const float*)d_in[0];
    const float* W = (const float*)d_in[1];
    const float* b = (const float*)d_in[2];
    float* out = (float*)d_out;
    mlp4_fused<<<dim3(MODELS * BLOCKS_PER_MODEL), dim3(256), 0, stream>>>(x, W, b, out);
}